// Round 1
// baseline (295.627 us; speedup 1.0000x reference)
//
#include <hip/hip_runtime.h>
#include <cstdint>

typedef __attribute__((ext_vector_type(8))) __bf16 bf16x8;
typedef __attribute__((ext_vector_type(4))) float f32x4;

#define DEV __device__ __forceinline__

DEV unsigned short f2bf(float f) {
    unsigned int u = __builtin_bit_cast(unsigned int, f);
    u += 0x7fffu + ((u >> 16) & 1u);   // RNE
    return (unsigned short)(u >> 16);
}
DEV __bf16 bits2bf(unsigned short u) { return __builtin_bit_cast(__bf16, u); }

DEV void async_copy16(const void* g, void* l) {
    __builtin_amdgcn_global_load_lds(
        (const __attribute__((address_space(1))) unsigned int*)g,
        (__attribute__((address_space(3))) unsigned int*)l, 16, 0, 0);
}

DEV f32x4 mfma16(bf16x8 a, bf16x8 b, f32x4 c) {
    return __builtin_amdgcn_mfma_f32_16x16x32_bf16(a, b, c, 0, 0, 0);
}

// ---------------- f32 -> bf16 convert (vectorized) ----------------
__global__ __launch_bounds__(256) void convert_bf16(const float* __restrict__ in,
                                                    unsigned short* __restrict__ outp, int n) {
    int i = (blockIdx.x * 256 + threadIdx.x) * 4;
    if (i >= n) return;
    float4 v = *(const float4*)&in[i];
    ushort4 o;
    o.x = f2bf(v.x); o.y = f2bf(v.y); o.z = f2bf(v.z); o.w = f2bf(v.w);
    *(ushort4*)&outp[i] = o;
}

// ---------------- W[K][N] f32 -> Wt[N][K] bf16 ----------------
__global__ __launch_bounds__(256) void transpose_convert(const float* __restrict__ W,
                                                         unsigned short* __restrict__ Wt,
                                                         int K, int N) {
    __shared__ float tile[32][33];
    int n0 = blockIdx.x * 32, k0 = blockIdx.y * 32;
    int tx = threadIdx.x & 31, ty = threadIdx.x >> 5;  // ty 0..7
#pragma unroll
    for (int i = 0; i < 32; i += 8)
        tile[ty + i][tx] = W[(size_t)(k0 + ty + i) * N + n0 + tx];
    __syncthreads();
#pragma unroll
    for (int i = 0; i < 32; i += 8)
        Wt[(size_t)(n0 + ty + i) * K + k0 + tx] = f2bf(tile[tx][ty + i]);
}

// ---------------- GEMM: C[M][N] = A[M][K] @ Bt[N][K]^T + bias ----------------
// 128x128 tile, BK=32, 4 waves (2x2 of 64x64), mfma 16x16x32 bf16.
template <int OUTF32>
__global__ __launch_bounds__(256) void gemm_bt(const unsigned short* __restrict__ A,
                                               const unsigned short* __restrict__ Bt,
                                               const float* __restrict__ bias,
                                               void* __restrict__ Cout,
                                               int M, int N, int K) {
    __shared__ __align__(16) unsigned short Asl[128][32];
    __shared__ __align__(16) unsigned short Bsl[128][32];
    const int tid = threadIdx.x;
    const int lane = tid & 63, w = tid >> 6;
    const int cl = lane & 15, kg = lane >> 4;
    const int m0 = blockIdx.x * 128, n0 = blockIdx.y * 128;
    const int wm = (w >> 1) * 64, wn = (w & 1) * 64;

    f32x4 acc[4][4] = {};

    // staging: wave w covers rows [w*32, w*32+32) of each tile, 2 chunks of 16 rows
    const int rs = lane >> 2, ks = (lane & 3) * 8;
    const unsigned short* ga = A + (size_t)(m0 + w * 32 + rs) * K + ks;
    const unsigned short* gb = Bt + (size_t)(n0 + w * 32 + rs) * K + ks;
    unsigned short* la = &Asl[w * 32][0];
    unsigned short* lb = &Bsl[w * 32][0];

    for (int k0 = 0; k0 < K; k0 += 32) {
        async_copy16(ga, la);
        async_copy16(ga + (size_t)16 * K, la + 512);
        async_copy16(gb, lb);
        async_copy16(gb + (size_t)16 * K, lb + 512);
        ga += 32; gb += 32;
        __syncthreads();

        bf16x8 af[4], bfv[4];
#pragma unroll
        for (int mf = 0; mf < 4; ++mf)
            af[mf] = *(const bf16x8*)&Asl[wm + mf * 16 + cl][kg * 8];
#pragma unroll
        for (int nf = 0; nf < 4; ++nf)
            bfv[nf] = *(const bf16x8*)&Bsl[wn + nf * 16 + cl][kg * 8];
#pragma unroll
        for (int mf = 0; mf < 4; ++mf)
#pragma unroll
            for (int nf = 0; nf < 4; ++nf)
                acc[mf][nf] = mfma16(af[mf], bfv[nf], acc[mf][nf]);
        __syncthreads();
    }

#pragma unroll
    for (int mf = 0; mf < 4; ++mf) {
#pragma unroll
        for (int nf = 0; nf < 4; ++nf) {
            const int col = n0 + wn + nf * 16 + cl;
            const float bv = bias[col];
#pragma unroll
            for (int r = 0; r < 4; ++r) {
                const int row = m0 + wm + mf * 16 + kg * 4 + r;
                const float v = acc[mf][nf][r] + bv;
                if (OUTF32)
                    ((float*)Cout)[(size_t)row * N + col] = v;
                else
                    ((unsigned short*)Cout)[(size_t)row * N + col] = f2bf(v);
            }
        }
    }
}

// ---------------- flash attention ----------------
// grid: (S/64, B*H). 4 independent waves/block, 16 q-rows each. Causal, scale=1/8.
__global__ __launch_bounds__(256) void attn_fwd(const unsigned short* __restrict__ qkv,  // [B*S][3072]
                                                unsigned short* __restrict__ aout) {     // [B*S][1024]
    constexpr int S = 2048, RS = 3072;
    __shared__ __align__(16) unsigned short Vlds[4][32][64];
    __shared__ __align__(16) unsigned short Plds[4][16][32];
    const int tid = threadIdx.x, lane = tid & 63, w = tid >> 6;
    const int cl = lane & 15, kg = lane >> 4;
    const int bh = blockIdx.y, b = bh >> 4, h = bh & 15;
    const int q0 = blockIdx.x * 64 + w * 16;
    const size_t base = (size_t)b * S * RS;
    const unsigned short* Qp = qkv + base + h * 64;
    const unsigned short* Kp = qkv + base + 1024 + h * 64;
    const unsigned short* Vp = qkv + base + 2048 + h * 64;

    bf16x8 qf[2];
#pragma unroll
    for (int f = 0; f < 2; ++f)
        qf[f] = *(const bf16x8*)&Qp[(size_t)(q0 + cl) * RS + f * 32 + kg * 8];

    float m[4], l[4];
    f32x4 oacc[4] = {};
#pragma unroll
    for (int r = 0; r < 4; ++r) { m[r] = -1e30f; l[r] = 0.f; }

    const int qhi = q0 + 15;
    for (int s0 = 0; s0 <= qhi; s0 += 32) {
        // ---- scores: S[16q][32k] = Q @ K^T ----
        f32x4 sacc[2] = {};
#pragma unroll
        for (int nf = 0; nf < 2; ++nf)
#pragma unroll
            for (int kf = 0; kf < 2; ++kf) {
                bf16x8 kb = *(const bf16x8*)&Kp[(size_t)(s0 + nf * 16 + cl) * RS + kf * 32 + kg * 8];
                sacc[nf] = mfma16(qf[kf], kb, sacc[nf]);
            }

        // ---- stage V [32keys][64d] linearly into this wave's LDS slice ----
        {
            const int key = lane >> 1, dh = (lane & 1) * 32;
            const unsigned short* src = Vp + (size_t)(s0 + key) * RS + dh;
#pragma unroll
            for (int c = 0; c < 4; ++c)
                *(uint4*)&Vlds[w][key][dh + c * 8] = *(const uint4*)&src[c * 8];
        }

        // ---- mask + online softmax (rows owned per (kg,r), cols across 16 lanes) ----
        const bool partial = (s0 + 31 > q0);
        float pv[2][4];
#pragma unroll
        for (int nf = 0; nf < 2; ++nf) {
            const int key = s0 + nf * 16 + cl;
#pragma unroll
            for (int r = 0; r < 4; ++r) {
                float sv = sacc[nf][r] * 0.125f;
                if (partial && (key > q0 + kg * 4 + r)) sv = -1e30f;
                pv[nf][r] = sv;
            }
        }
#pragma unroll
        for (int r = 0; r < 4; ++r) {
            float rx = fmaxf(pv[0][r], pv[1][r]);
#pragma unroll
            for (int off = 1; off < 16; off <<= 1) rx = fmaxf(rx, __shfl_xor(rx, off, 64));
            const float mn = fmaxf(m[r], rx);
            const float alpha = __expf(m[r] - mn);
            const float p0 = __expf(pv[0][r] - mn);
            const float p1 = __expf(pv[1][r] - mn);
            pv[0][r] = p0; pv[1][r] = p1;
            float rsum = p0 + p1;
#pragma unroll
            for (int off = 1; off < 16; off <<= 1) rsum += __shfl_xor(rsum, off, 64);
            l[r] = l[r] * alpha + rsum;
            m[r] = mn;
#pragma unroll
            for (int d = 0; d < 4; ++d) oacc[d][r] *= alpha;
        }

        // ---- P -> LDS (bf16) ----
#pragma unroll
        for (int nf = 0; nf < 2; ++nf)
#pragma unroll
            for (int r = 0; r < 4; ++r)
                Plds[w][kg * 4 + r][nf * 16 + cl] = f2bf(pv[nf][r]);

        // intra-wave cross-lane LDS visibility (no __syncthreads: waves diverge)
        asm volatile("s_waitcnt lgkmcnt(0)" ::: "memory");

        // ---- O += P[16][32] @ V[32][64] ----
        const bf16x8 pa = *(const bf16x8*)&Plds[w][cl][kg * 8];
#pragma unroll
        for (int df = 0; df < 4; ++df) {
            bf16x8 vb;
#pragma unroll
            for (int j = 0; j < 8; ++j) vb[j] = bits2bf(Vlds[w][kg * 8 + j][df * 16 + cl]);
            oacc[df] = mfma16(pa, vb, oacc[df]);
        }
    }

    // ---- epilogue: O /= l, write bf16 ----
#pragma unroll
    for (int df = 0; df < 4; ++df)
#pragma unroll
        for (int r = 0; r < 4; ++r) {
            const float v = oacc[df][r] / l[r];
            const int row = q0 + kg * 4 + r;
            aout[(size_t)(b * S + row) * 1024 + h * 64 + df * 16 + cl] = f2bf(v);
        }
}

extern "C" void kernel_launch(void* const* d_in, const int* in_sizes, int n_in,
                              void* d_out, int out_size, void* d_ws, size_t ws_size,
                              hipStream_t stream) {
    (void)in_sizes; (void)n_in; (void)out_size; (void)ws_size;
    const float* hs    = (const float*)d_in[0];  // [2,2048,1024]
    const float* wqkv  = (const float*)d_in[1];  // [1024,3072]
    const float* bqkv  = (const float*)d_in[2];  // [3072]
    const float* wproj = (const float*)d_in[3];  // [1024,1024]
    const float* bproj = (const float*)d_in[4];  // [1024]
    float* out = (float*)d_out;                  // [2,2048,1024] f32

    unsigned short* Xb  = (unsigned short*)d_ws;                 // 4096*1024
    unsigned short* Wqt = Xb  + (size_t)4096 * 1024;             // 3072*1024
    unsigned short* Wpt = Wqt + (size_t)3072 * 1024;             // 1024*1024
    unsigned short* QKV = Wpt + (size_t)1024 * 1024;             // 4096*3072
    unsigned short* AO  = QKV + (size_t)4096 * 3072;             // 4096*1024
    // total ws: 50,331,648 bytes

    convert_bf16<<<4096, 256, 0, stream>>>(hs, Xb, 4096 * 1024);
    transpose_convert<<<dim3(3072 / 32, 1024 / 32), 256, 0, stream>>>(wqkv, Wqt, 1024, 3072);
    transpose_convert<<<dim3(1024 / 32, 1024 / 32), 256, 0, stream>>>(wproj, Wpt, 1024, 1024);

    gemm_bt<0><<<dim3(32, 24), 256, 0, stream>>>(Xb, Wqt, bqkv, (void*)QKV, 4096, 3072, 1024);
    attn_fwd<<<dim3(32, 32), 256, 0, stream>>>(QKV, AO);
    gemm_bt<1><<<dim3(32, 8), 256, 0, stream>>>(AO, Wpt, bproj, (void*)out, 4096, 1024, 1024);
}

// Round 2
// 217.062 us; speedup vs baseline: 1.3619x; 1.3619x over previous
//
#include <hip/hip_runtime.h>
#include <cstdint>

typedef __attribute__((ext_vector_type(8))) __bf16 bf16x8;
typedef __attribute__((ext_vector_type(4))) float f32x4;

#define DEV __device__ __forceinline__

DEV unsigned short f2bf(float f) {
    unsigned int u = __builtin_bit_cast(unsigned int, f);
    u += 0x7fffu + ((u >> 16) & 1u);   // RNE
    return (unsigned short)(u >> 16);
}

DEV void async_copy16(const void* g, void* l) {
    __builtin_amdgcn_global_load_lds(
        (const __attribute__((address_space(1))) unsigned int*)g,
        (__attribute__((address_space(3))) unsigned int*)l, 16, 0, 0);
}

DEV f32x4 mfma16(bf16x8 a, bf16x8 b, f32x4 c) {
    return __builtin_amdgcn_mfma_f32_16x16x32_bf16(a, b, c, 0, 0, 0);
}

// ---------------- f32 -> bf16 convert (vectorized) ----------------
__global__ __launch_bounds__(256) void convert_bf16(const float* __restrict__ in,
                                                    unsigned short* __restrict__ outp, int n) {
    int i = (blockIdx.x * 256 + threadIdx.x) * 4;
    if (i >= n) return;
    float4 v = *(const float4*)&in[i];
    ushort4 o;
    o.x = f2bf(v.x); o.y = f2bf(v.y); o.z = f2bf(v.z); o.w = f2bf(v.w);
    *(ushort4*)&outp[i] = o;
}

// ---------------- W[K][N] f32 -> Wt[N][K] bf16 ----------------
__global__ __launch_bounds__(256) void transpose_convert(const float* __restrict__ W,
                                                         unsigned short* __restrict__ Wt,
                                                         int K, int N) {
    __shared__ float tile[32][33];
    int n0 = blockIdx.x * 32, k0 = blockIdx.y * 32;
    int tx = threadIdx.x & 31, ty = threadIdx.x >> 5;  // ty 0..7
#pragma unroll
    for (int i = 0; i < 32; i += 8)
        tile[ty + i][tx] = W[(size_t)(k0 + ty + i) * N + n0 + tx];
    __syncthreads();
#pragma unroll
    for (int i = 0; i < 32; i += 8)
        Wt[(size_t)(n0 + ty + i) * K + k0 + tx] = f2bf(tile[tx][ty + i]);
}

// ---------------- V part of QKV -> Vt[b][h][d][s] (bf16 -> bf16) ----------------
__global__ __launch_bounds__(256) void transpose_v(const unsigned short* __restrict__ qkv,
                                                   unsigned short* __restrict__ vt) {
    constexpr int S = 2048, RS = 3072;
    __shared__ unsigned short tile[32][33];
    const int s0 = blockIdx.x * 32, d0 = blockIdx.y * 32, bh = blockIdx.z;
    const int b = bh >> 4, h = bh & 15;
    const int tx = threadIdx.x & 31, ty = threadIdx.x >> 5;  // ty 0..7
#pragma unroll
    for (int i = 0; i < 32; i += 8)
        tile[ty + i][tx] = qkv[(size_t)(b * S + s0 + ty + i) * RS + 2048 + h * 64 + d0 + tx];
    __syncthreads();
#pragma unroll
    for (int i = 0; i < 32; i += 8)
        vt[(size_t)(bh * 64 + d0 + ty + i) * S + s0 + tx] = tile[tx][ty + i];
}

// ---------------- GEMM: C[M][N] = A[M][K] @ Bt[N][K]^T + bias ----------------
template <int OUTF32>
__global__ __launch_bounds__(256) void gemm_bt(const unsigned short* __restrict__ A,
                                               const unsigned short* __restrict__ Bt,
                                               const float* __restrict__ bias,
                                               void* __restrict__ Cout,
                                               int M, int N, int K) {
    __shared__ __align__(16) unsigned short Asl[128][32];
    __shared__ __align__(16) unsigned short Bsl[128][32];
    const int tid = threadIdx.x;
    const int lane = tid & 63, w = tid >> 6;
    const int cl = lane & 15, kg = lane >> 4;
    const int m0 = blockIdx.x * 128, n0 = blockIdx.y * 128;
    const int wm = (w >> 1) * 64, wn = (w & 1) * 64;

    f32x4 acc[4][4] = {};

    const int rs = lane >> 2, ks = (lane & 3) * 8;
    const unsigned short* ga = A + (size_t)(m0 + w * 32 + rs) * K + ks;
    const unsigned short* gb = Bt + (size_t)(n0 + w * 32 + rs) * K + ks;
    unsigned short* la = &Asl[w * 32][0];
    unsigned short* lb = &Bsl[w * 32][0];

    for (int k0 = 0; k0 < K; k0 += 32) {
        async_copy16(ga, la);
        async_copy16(ga + (size_t)16 * K, la + 512);
        async_copy16(gb, lb);
        async_copy16(gb + (size_t)16 * K, lb + 512);
        ga += 32; gb += 32;
        __syncthreads();

        bf16x8 af[4], bfv[4];
#pragma unroll
        for (int mf = 0; mf < 4; ++mf)
            af[mf] = *(const bf16x8*)&Asl[wm + mf * 16 + cl][kg * 8];
#pragma unroll
        for (int nf = 0; nf < 4; ++nf)
            bfv[nf] = *(const bf16x8*)&Bsl[wn + nf * 16 + cl][kg * 8];
#pragma unroll
        for (int mf = 0; mf < 4; ++mf)
#pragma unroll
            for (int nf = 0; nf < 4; ++nf)
                acc[mf][nf] = mfma16(af[mf], bfv[nf], acc[mf][nf]);
        __syncthreads();
    }

#pragma unroll
    for (int mf = 0; mf < 4; ++mf) {
#pragma unroll
        for (int nf = 0; nf < 4; ++nf) {
            const int col = n0 + wn + nf * 16 + cl;
            const float bv = bias[col];
#pragma unroll
            for (int r = 0; r < 4; ++r) {
                const int row = m0 + wm + mf * 16 + kg * 4 + r;
                const float v = acc[mf][nf][r] + bv;
                if (OUTF32)
                    ((float*)Cout)[(size_t)row * N + col] = v;
                else
                    ((unsigned short*)Cout)[(size_t)row * N + col] = f2bf(v);
            }
        }
    }
}

// ---------------- flash attention v2 ----------------
// grid: (16, 32). 4 independent waves/block, 32 q-rows each, KVBLK=64.
// K read direct from global (L2-fit), V read from pre-transposed Vt (contiguous frags).
// P staged through XOR-swizzled per-wave LDS.
__global__ __launch_bounds__(256) void attn_fwd2(const unsigned short* __restrict__ qkv,
                                                 const unsigned short* __restrict__ vt,
                                                 unsigned short* __restrict__ aout) {
    constexpr int S = 2048, RS = 3072;
    __shared__ __align__(16) unsigned short Plds[4][32 * 64];
    const int tid = threadIdx.x, lane = tid & 63, w = tid >> 6;
    const int cl = lane & 15, kg = lane >> 4;
    const int bh = blockIdx.y, b = bh >> 4, h = bh & 15;
    const int qstrip = (gridDim.x - 1) - blockIdx.x;   // heavy blocks first
    const int q0 = qstrip * 128 + w * 32;
    const unsigned short* Qp = qkv + (size_t)b * S * RS + h * 64;
    const unsigned short* Kp = Qp + 1024;
    const unsigned short* Vtp = vt + (size_t)bh * 64 * S;

    bf16x8 qf[2][2];
#pragma unroll
    for (int mr = 0; mr < 2; ++mr)
#pragma unroll
        for (int kf = 0; kf < 2; ++kf)
            qf[mr][kf] = *(const bf16x8*)&Qp[(size_t)(q0 + mr * 16 + cl) * RS + kf * 32 + kg * 8];

    float m[2][4], l[2][4];
    f32x4 oacc[2][4] = {};
#pragma unroll
    for (int mr = 0; mr < 2; ++mr)
#pragma unroll
        for (int r = 0; r < 4; ++r) { m[mr][r] = -1e30f; l[mr][r] = 0.f; }

    const int smax = q0 + 31;
    for (int s0 = 0; s0 <= smax; s0 += 64) {
        // ---- K frags from global (L2) ----
        bf16x8 kb[4][2];
#pragma unroll
        for (int nf = 0; nf < 4; ++nf)
#pragma unroll
            for (int kf = 0; kf < 2; ++kf)
                kb[nf][kf] = *(const bf16x8*)&Kp[(size_t)(s0 + nf * 16 + cl) * RS + kf * 32 + kg * 8];

        // ---- QK^T ----
        f32x4 sacc[2][4] = {};
        __builtin_amdgcn_s_setprio(1);
#pragma unroll
        for (int nf = 0; nf < 4; ++nf)
#pragma unroll
            for (int mr = 0; mr < 2; ++mr)
#pragma unroll
                for (int kf = 0; kf < 2; ++kf)
                    sacc[mr][nf] = mfma16(qf[mr][kf], kb[nf][kf], sacc[mr][nf]);
        __builtin_amdgcn_s_setprio(0);

        // ---- scale + causal mask ----
        const bool partial = (s0 + 63 > q0);
        float pv[2][4][4];
#pragma unroll
        for (int mr = 0; mr < 2; ++mr)
#pragma unroll
            for (int nf = 0; nf < 4; ++nf) {
                const int key = s0 + nf * 16 + cl;
#pragma unroll
                for (int r = 0; r < 4; ++r) {
                    float sv = sacc[mr][nf][r] * 0.125f;
                    if (partial && (key > q0 + mr * 16 + kg * 4 + r)) sv = -1e30f;
                    pv[mr][nf][r] = sv;
                }
            }

        // ---- row max (8 independent shfl chains) ----
        float rx[2][4];
#pragma unroll
        for (int mr = 0; mr < 2; ++mr)
#pragma unroll
            for (int r = 0; r < 4; ++r)
                rx[mr][r] = fmaxf(fmaxf(pv[mr][0][r], pv[mr][1][r]),
                                  fmaxf(pv[mr][2][r], pv[mr][3][r]));
#pragma unroll
        for (int off = 1; off < 16; off <<= 1)
#pragma unroll
            for (int mr = 0; mr < 2; ++mr)
#pragma unroll
                for (int r = 0; r < 4; ++r)
                    rx[mr][r] = fmaxf(rx[mr][r], __shfl_xor(rx[mr][r], off, 64));

        // ---- defer-max (T13): rescale only when max grew past threshold ----
        float need = 0.f;
#pragma unroll
        for (int mr = 0; mr < 2; ++mr)
#pragma unroll
            for (int r = 0; r < 4; ++r)
                need = fmaxf(need, rx[mr][r] - m[mr][r]);
        if (__any(need > 8.0f)) {
#pragma unroll
            for (int mr = 0; mr < 2; ++mr)
#pragma unroll
                for (int r = 0; r < 4; ++r) {
                    const float mn = fmaxf(m[mr][r], rx[mr][r]);
                    const float al = __expf(m[mr][r] - mn);
                    l[mr][r] *= al;
                    m[mr][r] = mn;
#pragma unroll
                    for (int df = 0; df < 4; ++df) oacc[mr][df][r] *= al;
                }
        }

        // ---- exp, P -> swizzled LDS, row sum ----
        float rs[2][4] = {};
#pragma unroll
        for (int mr = 0; mr < 2; ++mr)
#pragma unroll
            for (int nf = 0; nf < 4; ++nf)
#pragma unroll
                for (int r = 0; r < 4; ++r) {
                    const float p = __expf(pv[mr][nf][r] - m[mr][r]);
                    rs[mr][r] += p;
                    const int row = mr * 16 + kg * 4 + r;
                    const int col = nf * 16 + cl;
                    Plds[w][(row * 64 + col) ^ ((row & 7) << 3)] = f2bf(p);
                }
#pragma unroll
        for (int off = 1; off < 16; off <<= 1)
#pragma unroll
            for (int mr = 0; mr < 2; ++mr)
#pragma unroll
                for (int r = 0; r < 4; ++r)
                    rs[mr][r] += __shfl_xor(rs[mr][r], off, 64);
#pragma unroll
        for (int mr = 0; mr < 2; ++mr)
#pragma unroll
            for (int r = 0; r < 4; ++r)
                l[mr][r] += rs[mr][r];

        asm volatile("s_waitcnt lgkmcnt(0)" ::: "memory");
        __builtin_amdgcn_sched_barrier(0);

        // ---- O += P[32][64] @ V[64][64] (V frags contiguous from Vt) ----
#pragma unroll
        for (int ks = 0; ks < 2; ++ks) {
            bf16x8 pa[2];
#pragma unroll
            for (int mr = 0; mr < 2; ++mr) {
                const int row = mr * 16 + cl;
                pa[mr] = *(const bf16x8*)&Plds[w][(row * 64 + ks * 32 + kg * 8) ^ ((row & 7) << 3)];
            }
            __builtin_amdgcn_s_setprio(1);
#pragma unroll
            for (int df = 0; df < 4; ++df) {
                const bf16x8 vb = *(const bf16x8*)&Vtp[(size_t)(df * 16 + cl) * S + s0 + ks * 32 + kg * 8];
#pragma unroll
                for (int mr = 0; mr < 2; ++mr)
                    oacc[mr][df] = mfma16(pa[mr], vb, oacc[mr][df]);
            }
            __builtin_amdgcn_s_setprio(0);
        }
    }

    // ---- epilogue ----
#pragma unroll
    for (int mr = 0; mr < 2; ++mr)
#pragma unroll
        for (int df = 0; df < 4; ++df)
#pragma unroll
            for (int r = 0; r < 4; ++r) {
                const float v = oacc[mr][df][r] / l[mr][r];
                const int row = q0 + mr * 16 + kg * 4 + r;
                aout[(size_t)(b * S + row) * 1024 + h * 64 + df * 16 + cl] = f2bf(v);
            }
}

extern "C" void kernel_launch(void* const* d_in, const int* in_sizes, int n_in,
                              void* d_out, int out_size, void* d_ws, size_t ws_size,
                              hipStream_t stream) {
    (void)in_sizes; (void)n_in; (void)out_size; (void)ws_size;
    const float* hs    = (const float*)d_in[0];  // [2,2048,1024]
    const float* wqkv  = (const float*)d_in[1];  // [1024,3072]
    const float* bqkv  = (const float*)d_in[2];  // [3072]
    const float* wproj = (const float*)d_in[3];  // [1024,1024]
    const float* bproj = (const float*)d_in[4];  // [1024]
    float* out = (float*)d_out;                  // [2,2048,1024] f32

    unsigned short* Xb  = (unsigned short*)d_ws;                 // 4096*1024 (reused as Vt)
    unsigned short* Wqt = Xb  + (size_t)4096 * 1024;             // 3072*1024
    unsigned short* Wpt = Wqt + (size_t)3072 * 1024;             // 1024*1024
    unsigned short* QKV = Wpt + (size_t)1024 * 1024;             // 4096*3072
    unsigned short* AO  = QKV + (size_t)4096 * 3072;             // 4096*1024
    unsigned short* Vt  = Xb;  // X no longer needed after QKV GEMM; Vt = [32][64][2048]

    convert_bf16<<<4096, 256, 0, stream>>>(hs, Xb, 4096 * 1024);
    transpose_convert<<<dim3(3072 / 32, 1024 / 32), 256, 0, stream>>>(wqkv, Wqt, 1024, 3072);
    transpose_convert<<<dim3(1024 / 32, 1024 / 32), 256, 0, stream>>>(wproj, Wpt, 1024, 1024);

    gemm_bt<0><<<dim3(32, 24), 256, 0, stream>>>(Xb, Wqt, bqkv, (void*)QKV, 4096, 3072, 1024);
    transpose_v<<<dim3(64, 2, 32), 256, 0, stream>>>(QKV, Vt);
    attn_fwd2<<<dim3(16, 32), 256, 0, stream>>>(QKV, Vt, AO);
    gemm_bt<1><<<dim3(32, 8), 256, 0, stream>>>(AO, Wpt, bproj, (void*)out, 4096, 1024, 1024);
}

// Round 3
// 200.763 us; speedup vs baseline: 1.4725x; 1.0812x over previous
//
#include <hip/hip_runtime.h>
#include <cstdint>

typedef __attribute__((ext_vector_type(8))) __bf16 bf16x8;
typedef __attribute__((ext_vector_type(4))) float f32x4;
typedef __attribute__((ext_vector_type(16))) float f32x16;
typedef __attribute__((ext_vector_type(4))) unsigned int u32x4;

#define DEV __device__ __forceinline__

DEV unsigned short f2bf(float f) {
    unsigned int u = __builtin_bit_cast(unsigned int, f);
    u += 0x7fffu + ((u >> 16) & 1u);   // RNE
    return (unsigned short)(u >> 16);
}

DEV void async_copy16(const void* g, void* l) {
    __builtin_amdgcn_global_load_lds(
        (const __attribute__((address_space(1))) unsigned int*)g,
        (__attribute__((address_space(3))) unsigned int*)l, 16, 0, 0);
}

DEV f32x4 mfma16(bf16x8 a, bf16x8 b, f32x4 c) {
    return __builtin_amdgcn_mfma_f32_16x16x32_bf16(a, b, c, 0, 0, 0);
}
DEV f32x16 mfma32(bf16x8 a, bf16x8 b, f32x16 c) {
    return __builtin_amdgcn_mfma_f32_32x32x16_bf16(a, b, c, 0, 0, 0);
}
DEV unsigned int cvtpk(float lo, float hi) {
    unsigned int d;
    asm("v_cvt_pk_bf16_f32 %0, %1, %2" : "=v"(d) : "v"(lo), "v"(hi));
    return d;
}
DEV float exp2f_fast(float x) { return __builtin_amdgcn_exp2f(x); }

// ---------------- f32 -> bf16 convert (vectorized) ----------------
__global__ __launch_bounds__(256) void convert_bf16(const float* __restrict__ in,
                                                    unsigned short* __restrict__ outp, int n) {
    int i = (blockIdx.x * 256 + threadIdx.x) * 4;
    if (i >= n) return;
    float4 v = *(const float4*)&in[i];
    ushort4 o;
    o.x = f2bf(v.x); o.y = f2bf(v.y); o.z = f2bf(v.z); o.w = f2bf(v.w);
    *(ushort4*)&outp[i] = o;
}

// ---------------- W[K][N] f32 -> Wt[N][K] bf16 ----------------
__global__ __launch_bounds__(256) void transpose_convert(const float* __restrict__ W,
                                                         unsigned short* __restrict__ Wt,
                                                         int K, int N) {
    __shared__ float tile[32][33];
    int n0 = blockIdx.x * 32, k0 = blockIdx.y * 32;
    int tx = threadIdx.x & 31, ty = threadIdx.x >> 5;  // ty 0..7
#pragma unroll
    for (int i = 0; i < 32; i += 8)
        tile[ty + i][tx] = W[(size_t)(k0 + ty + i) * N + n0 + tx];
    __syncthreads();
#pragma unroll
    for (int i = 0; i < 32; i += 8)
        Wt[(size_t)(n0 + ty + i) * K + k0 + tx] = f2bf(tile[tx][ty + i]);
}

// ---------------- V part of QKV -> Vt[b][h][d][s] (bf16 -> bf16) ----------------
__global__ __launch_bounds__(256) void transpose_v(const unsigned short* __restrict__ qkv,
                                                   unsigned short* __restrict__ vt) {
    constexpr int S = 2048, RS = 3072;
    __shared__ unsigned short tile[32][33];
    const int s0 = blockIdx.x * 32, d0 = blockIdx.y * 32, bh = blockIdx.z;
    const int b = bh >> 4, h = bh & 15;
    const int tx = threadIdx.x & 31, ty = threadIdx.x >> 5;  // ty 0..7
#pragma unroll
    for (int i = 0; i < 32; i += 8)
        tile[ty + i][tx] = qkv[(size_t)(b * S + s0 + ty + i) * RS + 2048 + h * 64 + d0 + tx];
    __syncthreads();
#pragma unroll
    for (int i = 0; i < 32; i += 8)
        vt[(size_t)(bh * 64 + d0 + ty + i) * S + s0 + tx] = tile[tx][ty + i];
}

// ---------------- GEMM: C[M][N] = A[M][K] @ Bt[N][K]^T + bias ----------------
// cols < scaleN of the result are multiplied by scaleV (folds attn's softmax scale into Q).
template <int OUTF32>
__global__ __launch_bounds__(256) void gemm_bt(const unsigned short* __restrict__ A,
                                               const unsigned short* __restrict__ Bt,
                                               const float* __restrict__ bias,
                                               void* __restrict__ Cout,
                                               int M, int N, int K,
                                               int scaleN, float scaleV) {
    __shared__ __align__(16) unsigned short Asl[128][32];
    __shared__ __align__(16) unsigned short Bsl[128][32];
    const int tid = threadIdx.x;
    const int lane = tid & 63, w = tid >> 6;
    const int cl = lane & 15, kg = lane >> 4;
    const int m0 = blockIdx.x * 128, n0 = blockIdx.y * 128;
    const int wm = (w >> 1) * 64, wn = (w & 1) * 64;

    f32x4 acc[4][4] = {};

    const int rs = lane >> 2, ks = (lane & 3) * 8;
    const unsigned short* ga = A + (size_t)(m0 + w * 32 + rs) * K + ks;
    const unsigned short* gb = Bt + (size_t)(n0 + w * 32 + rs) * K + ks;
    unsigned short* la = &Asl[w * 32][0];
    unsigned short* lb = &Bsl[w * 32][0];

    for (int k0 = 0; k0 < K; k0 += 32) {
        async_copy16(ga, la);
        async_copy16(ga + (size_t)16 * K, la + 512);
        async_copy16(gb, lb);
        async_copy16(gb + (size_t)16 * K, lb + 512);
        ga += 32; gb += 32;
        __syncthreads();

        bf16x8 af[4], bfv[4];
#pragma unroll
        for (int mf = 0; mf < 4; ++mf)
            af[mf] = *(const bf16x8*)&Asl[wm + mf * 16 + cl][kg * 8];
#pragma unroll
        for (int nf = 0; nf < 4; ++nf)
            bfv[nf] = *(const bf16x8*)&Bsl[wn + nf * 16 + cl][kg * 8];
#pragma unroll
        for (int mf = 0; mf < 4; ++mf)
#pragma unroll
            for (int nf = 0; nf < 4; ++nf)
                acc[mf][nf] = mfma16(af[mf], bfv[nf], acc[mf][nf]);
        __syncthreads();
    }

#pragma unroll
    for (int mf = 0; mf < 4; ++mf) {
#pragma unroll
        for (int nf = 0; nf < 4; ++nf) {
            const int col = n0 + wn + nf * 16 + cl;
            const float bv = bias[col];
#pragma unroll
            for (int r = 0; r < 4; ++r) {
                const int row = m0 + wm + mf * 16 + kg * 4 + r;
                float v = acc[mf][nf][r] + bv;
                if (col < scaleN) v *= scaleV;
                if (OUTF32)
                    ((float*)Cout)[(size_t)row * N + col] = v;
                else
                    ((unsigned short*)Cout)[(size_t)row * N + col] = f2bf(v);
            }
        }
    }
}

// ---------------- flash attention v3: swapped-QK^T 32x32, in-register softmax ----------------
// grid (64, 32), block = 1 wave (64 threads). Each wave: 32 q-rows, KVBLK=64.
// Q pre-scaled by 0.125*log2e in the QKV GEMM -> softmax in exp2 domain.
__global__ __launch_bounds__(64) void attn_fwd3(const unsigned short* __restrict__ qkv,
                                                const unsigned short* __restrict__ vt,
                                                unsigned short* __restrict__ aout) {
    constexpr int S = 2048, RS = 3072;
    const int l = threadIdx.x & 63;
    const int q31 = l & 31, hi = l >> 5;
    const int bh = blockIdx.y, b = bh >> 4, h = bh & 15;
    const int qstrip = (int)gridDim.x - 1 - (int)blockIdx.x;   // heavy blocks first
    const int q0 = qstrip * 32;
    const int q = q0 + q31;
    const unsigned short* Qp = qkv + (size_t)b * S * RS + h * 64;
    const unsigned short* Kp = Qp + 1024;
    const unsigned short* Vtp = vt + (size_t)bh * 64 * S;

    bf16x8 qf[4];
#pragma unroll
    for (int kf = 0; kf < 4; ++kf)
        qf[kf] = *(const bf16x8*)&Qp[(size_t)q * RS + kf * 16 + hi * 8];

    float m = -1e30f, lsum = 0.f;
    f32x16 oacc[2] = {};

    const int smax = q0 + 31;

    // prologue: K tile 0
    bf16x8 kb[2][4];
#pragma unroll
    for (int kt = 0; kt < 2; ++kt)
#pragma unroll
        for (int kf = 0; kf < 4; ++kf)
            kb[kt][kf] = *(const bf16x8*)&Kp[(size_t)(kt * 32 + q31) * RS + kf * 16 + hi * 8];

    for (int s0 = 0; s0 <= smax; s0 += 64) {
        // V frags for this tile (issued early, consumed after softmax)
        bf16x8 vb[2][4];
#pragma unroll
        for (int df = 0; df < 2; ++df)
#pragma unroll
            for (int ks = 0; ks < 4; ++ks)
                vb[df][ks] = *(const bf16x8*)&Vtp[(size_t)(df * 32 + q31) * S + s0 + ks * 16 + hi * 8];

        // ---- T[key][q] = K @ Q^T (swapped) ----
        f32x16 tacc[2] = {};
        __builtin_amdgcn_s_setprio(1);
#pragma unroll
        for (int kt = 0; kt < 2; ++kt)
#pragma unroll
            for (int kf = 0; kf < 4; ++kf)
                tacc[kt] = mfma32(kb[kt][kf], qf[kf], tacc[kt]);
        __builtin_amdgcn_s_setprio(0);

        // ---- prefetch next K tile (hides under softmax+PV) ----
        if (s0 + 64 <= smax) {
#pragma unroll
            for (int kt = 0; kt < 2; ++kt)
#pragma unroll
                for (int kf = 0; kf < 4; ++kf)
                    kb[kt][kf] = *(const bf16x8*)&Kp[(size_t)(s0 + 64 + kt * 32 + q31) * RS + kf * 16 + hi * 8];
        }

        // ---- causal mask (lane l owns q-row l&31; keys in-lane) ----
        const bool partial = (s0 + 63 > q0);
        float pv[2][16];
#pragma unroll
        for (int kt = 0; kt < 2; ++kt)
#pragma unroll
            for (int r = 0; r < 16; ++r) {
                const int key = s0 + kt * 32 + (r & 3) + ((r >> 2) << 3) + hi * 4;
                float sv = tacc[kt][r];
                if (partial && key > q) sv = -1e30f;
                pv[kt][r] = sv;
            }

        // ---- row max: in-lane tree + one half-swap ----
        float rx = pv[0][0];
#pragma unroll
        for (int kt = 0; kt < 2; ++kt)
#pragma unroll
            for (int r = 0; r < 16; ++r) rx = fmaxf(rx, pv[kt][r]);
        rx = fmaxf(rx, __shfl_xor(rx, 32, 64));

        // ---- defer-max rescale (THR = 8*log2e) ----
        if (__any(rx - m > 11.5f)) {
            const float mn = fmaxf(m, rx);
            const float alpha = exp2f_fast(m - mn);
            lsum *= alpha;
            m = mn;
#pragma unroll
            for (int r = 0; r < 16; ++r) {
                const float ar = __shfl(alpha, (r & 3) + ((r >> 2) << 3) + hi * 4, 64);
                oacc[0][r] *= ar;
                oacc[1][r] *= ar;
            }
        }

        // ---- exp2 + pack to bf16 pairs + row sum ----
        unsigned int pk[2][4][2];
        float rsum = 0.f;
#pragma unroll
        for (int kt = 0; kt < 2; ++kt)
#pragma unroll
            for (int g = 0; g < 4; ++g) {
                const float e0 = exp2f_fast(pv[kt][g * 4 + 0] - m);
                const float e1 = exp2f_fast(pv[kt][g * 4 + 1] - m);
                const float e2 = exp2f_fast(pv[kt][g * 4 + 2] - m);
                const float e3 = exp2f_fast(pv[kt][g * 4 + 3] - m);
                pk[kt][g][0] = cvtpk(e0, e1);
                pk[kt][g][1] = cvtpk(e2, e3);
                rsum += (e0 + e1) + (e2 + e3);
            }
        rsum += __shfl_xor(rsum, 32, 64);
        lsum += rsum;

        // ---- PV: assemble PA frags in-register (half-swap), 8 mfma32 ----
#pragma unroll
        for (int ks = 0; ks < 4; ++ks) {
            const int kt = ks >> 1, kslo = ks & 1;
            const unsigned int pkA0 = pk[kt][2 * kslo][0],     pkA1 = pk[kt][2 * kslo][1];
            const unsigned int pkB0 = pk[kt][2 * kslo + 1][0], pkB1 = pk[kt][2 * kslo + 1][1];
            const unsigned int send0 = hi ? pkA0 : pkB0;
            const unsigned int send1 = hi ? pkA1 : pkB1;
            const unsigned int own0  = hi ? pkB0 : pkA0;
            const unsigned int own1  = hi ? pkB1 : pkA1;
            const unsigned int recv0 = (unsigned int)__shfl_xor((int)send0, 32, 64);
            const unsigned int recv1 = (unsigned int)__shfl_xor((int)send1, 32, 64);
            u32x4 u;
            u[0] = hi ? recv0 : own0;
            u[1] = hi ? recv1 : own1;
            u[2] = hi ? own0 : recv0;
            u[3] = hi ? own1 : recv1;
            const bf16x8 pa = __builtin_bit_cast(bf16x8, u);
            __builtin_amdgcn_s_setprio(1);
            oacc[0] = mfma32(pa, vb[0][ks], oacc[0]);
            oacc[1] = mfma32(pa, vb[1][ks], oacc[1]);
            __builtin_amdgcn_s_setprio(0);
        }
    }

    // ---- epilogue: O /= l ----
    const float linv = 1.f / lsum;
#pragma unroll
    for (int r = 0; r < 16; ++r) {
        const int qrow = (r & 3) + ((r >> 2) << 3) + hi * 4;
        const float lr = __shfl(linv, qrow, 64);
        const int row = q0 + qrow;
#pragma unroll
        for (int df = 0; df < 2; ++df)
            aout[(size_t)(b * S + row) * 1024 + h * 64 + df * 32 + q31] = f2bf(oacc[df][r] * lr);
    }
}

extern "C" void kernel_launch(void* const* d_in, const int* in_sizes, int n_in,
                              void* d_out, int out_size, void* d_ws, size_t ws_size,
                              hipStream_t stream) {
    (void)in_sizes; (void)n_in; (void)out_size; (void)ws_size;
    const float* hs    = (const float*)d_in[0];  // [2,2048,1024]
    const float* wqkv  = (const float*)d_in[1];  // [1024,3072]
    const float* bqkv  = (const float*)d_in[2];  // [3072]
    const float* wproj = (const float*)d_in[3];  // [1024,1024]
    const float* bproj = (const float*)d_in[4];  // [1024]
    float* out = (float*)d_out;                  // [2,2048,1024] f32

    unsigned short* Xb  = (unsigned short*)d_ws;                 // 4096*1024 (reused as Vt)
    unsigned short* Wqt = Xb  + (size_t)4096 * 1024;             // 3072*1024
    unsigned short* Wpt = Wqt + (size_t)3072 * 1024;             // 1024*1024
    unsigned short* QKV = Wpt + (size_t)1024 * 1024;             // 4096*3072
    unsigned short* AO  = QKV + (size_t)4096 * 3072;             // 4096*1024
    unsigned short* Vt  = Xb;  // X dead after QKV GEMM; Vt = [32 bh][64 d][2048 s]

    const float qscale = 0.125f * 1.4426950408889634f;  // fold softmax scale + log2e into Q

    convert_bf16<<<4096, 256, 0, stream>>>(hs, Xb, 4096 * 1024);
    transpose_convert<<<dim3(3072 / 32, 1024 / 32), 256, 0, stream>>>(wqkv, Wqt, 1024, 3072);
    transpose_convert<<<dim3(1024 / 32, 1024 / 32), 256, 0, stream>>>(wproj, Wpt, 1024, 1024);

    gemm_bt<0><<<dim3(32, 24), 256, 0, stream>>>(Xb, Wqt, bqkv, (void*)QKV, 4096, 3072, 1024,
                                                 1024, qscale);
    transpose_v<<<dim3(64, 2, 32), 256, 0, stream>>>(QKV, Vt);
    attn_fwd3<<<dim3(64, 32), 64, 0, stream>>>(QKV, Vt, AO);
    gemm_bt<1><<<dim3(32, 8), 256, 0, stream>>>(AO, Wpt, bproj, (void*)out, 4096, 1024, 1024,
                                                0, 1.0f);
}